// Round 9
// baseline (453.193 us; speedup 1.0000x reference)
//
#include <hip/hip_runtime.h>
#include <hip/hip_bf16.h>

// Problem constants (match reference)
constexpr int cB  = 8;
constexpr int cS  = 4096;
constexpr int cH  = 768;
constexpr int cNH = 12;
constexpr int cL  = 2;
constexpr int cNS = 64;
constexpr int cDH = 64;
constexpr int cM  = cB * cNS;  // 512 rows of activations

// ---- MEASUREMENT ROUND #2: amplify the three UNMEASURED kernels of the
// ---- best pipeline (R7, 283us) so they rise above the ~58us harness fills
// ---- and we get their true dur + counters. Idempotent reps. True time =
// ---- shown / REP. qkv and ln stay x1 (small, structurally simple).
constexpr int REP_PREP = 3;
constexpr int REP_ATTN = 8;
constexpr int REP_OG   = 8;

typedef __attribute__((ext_vector_type(8))) short bf16x8;
typedef __attribute__((ext_vector_type(4))) float f32x4;

__device__ __forceinline__ unsigned short f2b(float f) {
    __hip_bfloat16 h = __float2bfloat16(f);
    return *(unsigned short*)&h;
}

// ---------------------------------------------------------------------------
// 1) Fused prep, 768 threads/block (R7 version), REP_PREP reps.
// ---------------------------------------------------------------------------
union PrepShared {
    struct { int cnt; int list[cS]; float ps[3][192][4]; } p;  // 25.6 KB
    float T[3][64][65];                                        // 49.9 KB
};

__global__ __launch_bounds__(768) void prep_kernel(
    const int* __restrict__ sent_ind, const float* __restrict__ sl,
    __hip_bfloat16* __restrict__ xb,
    const float* __restrict__ Wq, const float* __restrict__ Wk,
    const float* __restrict__ Wv, const float* __restrict__ Wo,
    __hip_bfloat16* __restrict__ wt)
{
    __shared__ PrepShared sh;
    int tid = threadIdx.x;

    #pragma unroll 1
    for (int rep = 0; rep < REP_PREP; ++rep) {
    if (blockIdx.x < (unsigned)cM) {
        // ---------------- pool ----------------
        int bn = blockIdx.x;
        int b = bn >> 6, n = bn & (cNS - 1);
        if (tid == 0) sh.p.cnt = 0;
        __syncthreads();
        const int* si = sent_ind + (size_t)b * cS;
        for (int s = tid; s < cS; s += 768)
            if (s != 0 && si[s] == n) { int p = atomicAdd(&sh.p.cnt, 1); sh.p.list[p] = s; }
        __syncthreads();
        int c = sh.p.cnt;
        int grp = tid / 192;         // 0..3 row-groups
        int t   = tid % 192;
        int qtr = c >> 2;
        int lo = grp * qtr;
        int hi = (grp == 3) ? c : lo + qtr;
        const float* bbase = sl + (size_t)b * cS * cH;
        int col = t * 4;
        float4 a0 = {0.f, 0.f, 0.f, 0.f};
        float4 a1 = {0.f, 0.f, 0.f, 0.f};
        float4 a2 = {0.f, 0.f, 0.f, 0.f};
        float4 a3 = {0.f, 0.f, 0.f, 0.f};
        int i = lo;
        for (; i + 4 <= hi; i += 4) {
            float4 r0 = *(const float4*)(bbase + (size_t)sh.p.list[i + 0] * cH + col);
            float4 r1 = *(const float4*)(bbase + (size_t)sh.p.list[i + 1] * cH + col);
            float4 r2 = *(const float4*)(bbase + (size_t)sh.p.list[i + 2] * cH + col);
            float4 r3 = *(const float4*)(bbase + (size_t)sh.p.list[i + 3] * cH + col);
            a0.x += r0.x; a0.y += r0.y; a0.z += r0.z; a0.w += r0.w;
            a1.x += r1.x; a1.y += r1.y; a1.z += r1.z; a1.w += r1.w;
            a2.x += r2.x; a2.y += r2.y; a2.z += r2.z; a2.w += r2.w;
            a3.x += r3.x; a3.y += r3.y; a3.z += r3.z; a3.w += r3.w;
        }
        for (; i < hi; ++i) {
            float4 r0 = *(const float4*)(bbase + (size_t)sh.p.list[i] * cH + col);
            a0.x += r0.x; a0.y += r0.y; a0.z += r0.z; a0.w += r0.w;
        }
        float s0 = a0.x + a1.x + a2.x + a3.x;
        float s1 = a0.y + a1.y + a2.y + a3.y;
        float s2 = a0.z + a1.z + a2.z + a3.z;
        float s3 = a0.w + a1.w + a2.w + a3.w;
        if (grp) {
            sh.p.ps[grp - 1][t][0] = s0; sh.p.ps[grp - 1][t][1] = s1;
            sh.p.ps[grp - 1][t][2] = s2; sh.p.ps[grp - 1][t][3] = s3;
        }
        __syncthreads();
        if (grp == 0) {
            float inv = 1.0f / (float)c;
            s0 += sh.p.ps[0][t][0] + sh.p.ps[1][t][0] + sh.p.ps[2][t][0];
            s1 += sh.p.ps[0][t][1] + sh.p.ps[1][t][1] + sh.p.ps[2][t][1];
            s2 += sh.p.ps[0][t][2] + sh.p.ps[1][t][2] + sh.p.ps[2][t][2];
            s3 += sh.p.ps[0][t][3] + sh.p.ps[1][t][3] + sh.p.ps[2][t][3];
            __hip_bfloat16* xr = xb + (size_t)bn * cH + col;
            xr[0] = __float2bfloat16(s0 * inv);
            xr[1] = __float2bfloat16(s1 * inv);
            xr[2] = __float2bfloat16(s2 * inv);
            xr[3] = __float2bfloat16(s3 * inv);
        }
    } else {
        // ---------------- wconv: 3 tiles per block ----------------
        int sub = tid >> 8;                         // 0..2
        int t   = tid & 255;
        int bi = (blockIdx.x - cM) * 3 + sub;       // 0..1151 = (12 x 12 x 8)
        int bx = bi % 12, by = (bi / 12) % 12, mat = bi / 144;
        int layer = mat >> 2, which = mat & 3;
        const float* W = (which == 0 ? Wq : which == 1 ? Wk : which == 2 ? Wv : Wo)
                         + (size_t)layer * cH * cH;
        int k0 = by * 64, n0 = bx * 64;
        int r = t >> 2, cb = (t & 3) * 16;
        #pragma unroll
        for (int u = 0; u < 4; ++u) {
            float4 w4 = *(const float4*)(W + (size_t)(k0 + r) * cH + n0 + cb + u * 4);
            sh.T[sub][r][cb + u * 4 + 0] = w4.x; sh.T[sub][r][cb + u * 4 + 1] = w4.y;
            sh.T[sub][r][cb + u * 4 + 2] = w4.z; sh.T[sub][r][cb + u * 4 + 3] = w4.w;
        }
        __syncthreads();
        int nn = t >> 2, kseg = (t & 3) * 16;
        __hip_bfloat16 tmp[16] __attribute__((aligned(16)));
        #pragma unroll
        for (int j = 0; j < 16; ++j)
            tmp[j] = __float2bfloat16(sh.T[sub][kseg + j][nn]);
        __hip_bfloat16* dst = wt + ((size_t)mat * cH + n0 + nn) * cH + k0 + kseg;
        *(bf16x8*)(dst)     = *(const bf16x8*)(tmp);
        *(bf16x8*)(dst + 8) = *(const bf16x8*)(tmp + 8);
    }
    __syncthreads();   // rep boundary: LDS reuse guard
    }
}

// ---------------------------------------------------------------------------
// 2a) QKV GEMM, full-machine (R7, x1): 288 blocks x 256 thr.
// ---------------------------------------------------------------------------
__global__ __launch_bounds__(256) void qkv_kernel(
    const __hip_bfloat16* __restrict__ x_bf,
    const __hip_bfloat16* __restrict__ wqkv,
    const float* __restrict__ bq, const float* __restrict__ bk,
    const float* __restrict__ bv,
    __hip_bfloat16* __restrict__ q_bf, __hip_bfloat16* __restrict__ k_bf,
    __hip_bfloat16* __restrict__ v_bf)
{
    int tid = threadIdx.x;
    int lane = tid & 63, wave = tid >> 6;
    int l15 = lane & 15, q4 = lane >> 4;
    int mb = blockIdx.x & 7;
    int nb = blockIdx.x >> 3;
    int mat = nb / 12, hh = nb % 12;

    const __hip_bfloat16* Arow = x_bf
        + (size_t)(mb * 64 + wave * 16 + l15) * cH + q4 * 8;
    const __hip_bfloat16* Brow = wqkv + (size_t)mat * cH * cH
        + (size_t)(hh * 64 + l15) * cH + q4 * 8;

    f32x4 acc[4];
    #pragma unroll
    for (int nt = 0; nt < 4; ++nt) acc[nt] = (f32x4){0.f, 0.f, 0.f, 0.f};

    bf16x8 a, bw[4], an, bn[4];
    a = *(const bf16x8*)(Arow);
    #pragma unroll
    for (int nt = 0; nt < 4; ++nt)
        bw[nt] = *(const bf16x8*)(Brow + (size_t)nt * 16 * cH);
    #pragma unroll 4
    for (int k0 = 0; k0 < cH; k0 += 32) {
        if (k0 + 32 < cH) {
            an = *(const bf16x8*)(Arow + k0 + 32);
            #pragma unroll
            for (int nt = 0; nt < 4; ++nt)
                bn[nt] = *(const bf16x8*)(Brow + (size_t)nt * 16 * cH + k0 + 32);
        }
        #pragma unroll
        for (int nt = 0; nt < 4; ++nt)
            acc[nt] = __builtin_amdgcn_mfma_f32_16x16x32_bf16(a, bw[nt], acc[nt], 0, 0, 0);
        a = an;
        #pragma unroll
        for (int nt = 0; nt < 4; ++nt) bw[nt] = bn[nt];
    }

    const float* bias = mat == 0 ? bq : mat == 1 ? bk : bv;
    __hip_bfloat16* dst = (mat == 0 ? q_bf : mat == 1 ? k_bf : v_bf)
                          + (size_t)(mb * cNH + hh) * 4096;
    float qs = (mat == 0) ? 0.125f : 1.0f;
    #pragma unroll
    for (int nt = 0; nt < 4; ++nt) {
        int col = nt * 16 + l15;
        float bv_ = bias[hh * 64 + col];
        #pragma unroll
        for (int r = 0; r < 4; ++r) {
            int s = wave * 16 + q4 * 4 + r;
            dst[(size_t)s * 64 + col] = __float2bfloat16((acc[nt][r] + bv_) * qs);
        }
    }
}

// ---------------------------------------------------------------------------
// 2b) Attention, all-MFMA (R7), REP_ATTN reps: 96 blocks x 256 thr.
// ---------------------------------------------------------------------------
struct Attn2Shared {
    float S[cNS][cNS + 4];
    unsigned short Vt[cDH][cNS + 8];
    unsigned short P[cNS][cNS + 8];
};

__global__ __launch_bounds__(256) void attn2_kernel(
    const __hip_bfloat16* __restrict__ q_bf,
    const __hip_bfloat16* __restrict__ k_bf,
    const __hip_bfloat16* __restrict__ v_bf,
    __hip_bfloat16* __restrict__ ctx_bf)
{
    __shared__ Attn2Shared sh;
    int tid = threadIdx.x;
    int lane = tid & 63, wave = tid >> 6;
    int l15 = lane & 15, q4 = lane >> 4;
    int bh = blockIdx.x, b = bh / cNH, h = bh % cNH;
    const __hip_bfloat16* qp = q_bf + (size_t)bh * 4096;
    const __hip_bfloat16* kp = k_bf + (size_t)bh * 4096;
    const __hip_bfloat16* vp = v_bf + (size_t)bh * 4096;

    #pragma unroll 1
    for (int rep = 0; rep < REP_ATTN; ++rep) {

    // stage V^T into LDS
    #pragma unroll
    for (int i = 0; i < 2; ++i) {
        int idx = tid + i * 256;
        int s = idx >> 3, c0 = (idx & 7) * 8;
        bf16x8 v8 = *(const bf16x8*)(vp + (size_t)s * 64 + c0);
        #pragma unroll
        for (int j = 0; j < 8; ++j)
            sh.Vt[c0 + j][s] = (unsigned short)v8[j];
    }

    // QK^T
    {
        bf16x8 aq0 = *(const bf16x8*)(qp + (size_t)(wave * 16 + l15) * 64 + q4 * 8);
        bf16x8 aq1 = *(const bf16x8*)(qp + (size_t)(wave * 16 + l15) * 64 + 32 + q4 * 8);
        #pragma unroll
        for (int ct = 0; ct < 4; ++ct) {
            bf16x8 bk0 = *(const bf16x8*)(kp + (size_t)(ct * 16 + l15) * 64 + q4 * 8);
            bf16x8 bk1 = *(const bf16x8*)(kp + (size_t)(ct * 16 + l15) * 64 + 32 + q4 * 8);
            f32x4 sc = (f32x4){0.f, 0.f, 0.f, 0.f};
            sc = __builtin_amdgcn_mfma_f32_16x16x32_bf16(aq0, bk0, sc, 0, 0, 0);
            sc = __builtin_amdgcn_mfma_f32_16x16x32_bf16(aq1, bk1, sc, 0, 0, 0);
            #pragma unroll
            for (int r = 0; r < 4; ++r)
                sh.S[wave * 16 + q4 * 4 + r][ct * 16 + l15] = sc[r];
        }
    }
    __syncthreads();

    {   // softmax
        int row = tid >> 2, jq = tid & 3;
        float e[16];
        float m = -1e30f;
        #pragma unroll
        for (int c = 0; c < 16; ++c) { e[c] = sh.S[row][jq * 16 + c]; m = fmaxf(m, e[c]); }
        m = fmaxf(m, __shfl_xor(m, 1));
        m = fmaxf(m, __shfl_xor(m, 2));
        float s = 0.f;
        #pragma unroll
        for (int c = 0; c < 16; ++c) { e[c] = __expf(e[c] - m); s += e[c]; }
        s += __shfl_xor(s, 1);
        s += __shfl_xor(s, 2);
        float inv = 1.0f / s;
        #pragma unroll
        for (int c = 0; c < 16; ++c) sh.P[row][jq * 16 + c] = f2b(e[c] * inv);
    }
    __syncthreads();

    // PV
    {
        bf16x8 ap0 = *(const bf16x8*)&sh.P[wave * 16 + l15][q4 * 8];
        bf16x8 ap1 = *(const bf16x8*)&sh.P[wave * 16 + l15][32 + q4 * 8];
        #pragma unroll
        for (int dt = 0; dt < 4; ++dt) {
            bf16x8 bv0 = *(const bf16x8*)&sh.Vt[dt * 16 + l15][q4 * 8];
            bf16x8 bv1 = *(const bf16x8*)&sh.Vt[dt * 16 + l15][32 + q4 * 8];
            f32x4 o = (f32x4){0.f, 0.f, 0.f, 0.f};
            o = __builtin_amdgcn_mfma_f32_16x16x32_bf16(ap0, bv0, o, 0, 0, 0);
            o = __builtin_amdgcn_mfma_f32_16x16x32_bf16(ap1, bv1, o, 0, 0, 0);
            #pragma unroll
            for (int r = 0; r < 4; ++r) {
                int q = wave * 16 + q4 * 4 + r;
                ctx_bf[(size_t)(b * cNS + q) * cH + h * cDH + dt * 16 + l15] =
                    __float2bfloat16(o[r]);
            }
        }
    }
    __syncthreads();   // rep boundary: Vt/S/P reuse guard
    }
}

// ---------------------------------------------------------------------------
// 3) O-GEMM + bias + GELU (baseline kernel), REP_OG reps. Grid (24,8).
// ---------------------------------------------------------------------------
__global__ __launch_bounds__(256) void ogemm_kernel(
    const __hip_bfloat16* __restrict__ A,
    const __hip_bfloat16* __restrict__ Wt,
    const float* __restrict__ bias,
    __hip_bfloat16* __restrict__ C)
{
    int lane = threadIdx.x & 63;
    int wave = threadIdx.x >> 6;
    int l15 = lane & 15, q4 = lane >> 4;
    int m0 = blockIdx.y * 64 + wave * 16;
    int n0 = blockIdx.x * 32;

    const __hip_bfloat16* Arow = A  + (size_t)(m0 + l15) * cH + q4 * 8;
    const __hip_bfloat16* Wr0  = Wt + (size_t)(n0 + l15) * cH + q4 * 8;
    const __hip_bfloat16* Wr1  = Wr0 + (size_t)16 * cH;

    #pragma unroll 1
    for (int rep = 0; rep < REP_OG; ++rep) {
    f32x4 acc0 = {0.f, 0.f, 0.f, 0.f};
    f32x4 acc1 = {0.f, 0.f, 0.f, 0.f};
    #pragma unroll 8
    for (int k0 = 0; k0 < cH; k0 += 32) {
        bf16x8 a  = *(const bf16x8*)(Arow + k0);
        bf16x8 b0 = *(const bf16x8*)(Wr0 + k0);
        bf16x8 b1 = *(const bf16x8*)(Wr1 + k0);
        acc0 = __builtin_amdgcn_mfma_f32_16x16x32_bf16(a, b0, acc0, 0, 0, 0);
        acc1 = __builtin_amdgcn_mfma_f32_16x16x32_bf16(a, b1, acc1, 0, 0, 0);
    }
    #pragma unroll
    for (int nt = 0; nt < 2; ++nt) {
        const f32x4 acc = nt == 0 ? acc0 : acc1;
        int col = n0 + nt * 16 + l15;
        float bv = bias[col];
        #pragma unroll
        for (int r = 0; r < 4; ++r) {
            float v = acc[r] + bv;
            v = 0.5f * v * (1.0f + erff(v * 0.70710678118654752f));
            C[(size_t)(m0 + q4 * 4 + r) * cH + col] = __float2bfloat16(v);
        }
    }
    }
}

// ---------------------------------------------------------------------------
// 4) LayerNorm (baseline kernel, x1). 512 blocks.
// ---------------------------------------------------------------------------
__global__ __launch_bounds__(256) void ln_kernel(
    const __hip_bfloat16* __restrict__ h, const float* __restrict__ g,
    const float* __restrict__ bb, __hip_bfloat16* __restrict__ xb,
    float* __restrict__ outf)
{
    int row = blockIdx.x;
    const __hip_bfloat16* r = h + (size_t)row * cH;
    int tid = threadIdx.x;
    float v0 = __bfloat162float(r[tid]);
    float v1 = __bfloat162float(r[tid + 256]);
    float v2 = __bfloat162float(r[tid + 512]);
    float s = v0 + v1 + v2;
    __shared__ float red[4];
    #pragma unroll
    for (int o = 32; o; o >>= 1) s += __shfl_xor(s, o);
    if ((tid & 63) == 0) red[tid >> 6] = s;
    __syncthreads();
    float mu = (red[0] + red[1] + red[2] + red[3]) * (1.0f / 768.0f);
    float d0 = v0 - mu, d1 = v1 - mu, d2 = v2 - mu;
    float ss = d0 * d0 + d1 * d1 + d2 * d2;
    __syncthreads();
    #pragma unroll
    for (int o = 32; o; o >>= 1) ss += __shfl_xor(ss, o);
    if ((tid & 63) == 0) red[tid >> 6] = ss;
    __syncthreads();
    float var = (red[0] + red[1] + red[2] + red[3]) * (1.0f / 768.0f);
    float inv = rsqrtf(var + 1e-12f);
    float o0 = d0 * inv * g[tid]       + bb[tid];
    float o1 = d1 * inv * g[tid + 256] + bb[tid + 256];
    float o2 = d2 * inv * g[tid + 512] + bb[tid + 512];
    __hip_bfloat16* xr = xb + (size_t)row * cH;
    xr[tid]       = __float2bfloat16(o0);
    xr[tid + 256] = __float2bfloat16(o1);
    xr[tid + 512] = __float2bfloat16(o2);
    if (outf) {
        float* orow = outf + (size_t)row * cH;
        orow[tid] = o0; orow[tid + 256] = o1; orow[tid + 512] = o2;
    }
}

// ---------------------------------------------------------------------------
extern "C" void kernel_launch(void* const* d_in, const int* in_sizes, int n_in,
                              void* d_out, int out_size, void* d_ws, size_t ws_size,
                              hipStream_t stream) {
    const int*   sent_ind = (const int*)d_in[0];
    const float* start    = (const float*)d_in[1];
    const float* Wq = (const float*)d_in[2];
    const float* bq = (const float*)d_in[3];
    const float* Wk = (const float*)d_in[4];
    const float* bk = (const float*)d_in[5];
    const float* Wv = (const float*)d_in[6];
    const float* bv = (const float*)d_in[7];
    const float* Wo = (const float*)d_in[8];
    const float* bo = (const float*)d_in[9];
    const float* ln_g = (const float*)d_in[10];
    const float* ln_b = (const float*)d_in[11];
    float* out = (float*)d_out;

    char* w = (char*)d_ws;
    const size_t MH = 786432;  // M*H bf16 bytes
    __hip_bfloat16* wt     = (__hip_bfloat16*)w;
    __hip_bfloat16* x_bf   = (__hip_bfloat16*)(w + 9437184);
    __hip_bfloat16* ctx_bf = (__hip_bfloat16*)(w + 9437184 + MH);
    __hip_bfloat16* hb     = (__hip_bfloat16*)(w + 9437184 + 2 * MH);
    __hip_bfloat16* q_bf   = (__hip_bfloat16*)(w + 9437184 + 3 * MH);
    __hip_bfloat16* k_bf   = (__hip_bfloat16*)(w + 9437184 + 4 * MH);
    __hip_bfloat16* v_bf   = (__hip_bfloat16*)(w + 9437184 + 5 * MH);

    prep_kernel<<<cM + 384, 768, 0, stream>>>(sent_ind, start, x_bf,
                                              Wq, Wk, Wv, Wo, wt);

    for (int i = 0; i < cL; ++i) {
        const __hip_bfloat16* wqkv = wt + (size_t)(i * 4) * cH * cH;
        const __hip_bfloat16* wto  = wt + (size_t)(i * 4 + 3) * cH * cH;
        qkv_kernel<<<288, 256, 0, stream>>>(
            x_bf, wqkv, bq + (size_t)i * cH, bk + (size_t)i * cH, bv + (size_t)i * cH,
            q_bf, k_bf, v_bf);
        attn2_kernel<<<cB * cNH, 256, 0, stream>>>(q_bf, k_bf, v_bf, ctx_bf);
        ogemm_kernel<<<dim3(24, 8), 256, 0, stream>>>(
            ctx_bf, wto, bo + (size_t)i * cH, hb);
        ln_kernel<<<cM, 256, 0, stream>>>(
            hb, ln_g + (size_t)i * cH, ln_b + (size_t)i * cH,
            x_bf, (i == cL - 1) ? out : nullptr);
    }
}

// Round 10
// 282.065 us; speedup vs baseline: 1.6067x; 1.6067x over previous
//
#include <hip/hip_runtime.h>
#include <hip/hip_bf16.h>

// Problem constants (match reference)
constexpr int cB  = 8;
constexpr int cS  = 4096;
constexpr int cH  = 768;
constexpr int cNH = 12;
constexpr int cL  = 2;
constexpr int cNS = 64;
constexpr int cDH = 64;
constexpr int cM  = cB * cNS;  // 512 rows of activations

typedef __attribute__((ext_vector_type(8))) short bf16x8;
typedef __attribute__((ext_vector_type(4))) float f32x4;

__device__ __forceinline__ unsigned short f2b(float f) {
    __hip_bfloat16 h = __float2bfloat16(f);
    return *(unsigned short*)&h;
}

// ---------------------------------------------------------------------------
// 1) Fused prep, 768 threads/block. Pool: four 192-thread row-groups, now
//    EIGHT float4 streams in flight per thread (was 4) -- R9 counters show
//    latency-bound (VALUBusy 7%, occ 55%, BW under floor); depth-8 halves
//    dependent round-trips. wconv: 3 tiles/block (unchanged, R7-verified).
// ---------------------------------------------------------------------------
union PrepShared {
    struct { int cnt; int list[cS]; float ps[3][192][4]; } p;  // 25.6 KB
    float T[3][64][65];                                        // 49.9 KB
};

__global__ __launch_bounds__(768) void prep_kernel(
    const int* __restrict__ sent_ind, const float* __restrict__ sl,
    __hip_bfloat16* __restrict__ xb,
    const float* __restrict__ Wq, const float* __restrict__ Wk,
    const float* __restrict__ Wv, const float* __restrict__ Wo,
    __hip_bfloat16* __restrict__ wt)
{
    __shared__ PrepShared sh;
    int tid = threadIdx.x;

    if (blockIdx.x < (unsigned)cM) {
        // ---------------- pool ----------------
        int bn = blockIdx.x;
        int b = bn >> 6, n = bn & (cNS - 1);
        if (tid == 0) sh.p.cnt = 0;
        __syncthreads();
        const int* si = sent_ind + (size_t)b * cS;
        for (int s = tid; s < cS; s += 768)
            if (s != 0 && si[s] == n) { int p = atomicAdd(&sh.p.cnt, 1); sh.p.list[p] = s; }
        __syncthreads();
        int c = sh.p.cnt;
        int grp = tid / 192;         // 0..3 row-groups
        int t   = tid % 192;
        int qtr = c >> 2;
        int lo = grp * qtr;
        int hi = (grp == 3) ? c : lo + qtr;
        const float* bbase = sl + (size_t)b * cS * cH;
        int col = t * 4;
        float4 a[8];
        #pragma unroll
        for (int j = 0; j < 8; ++j) a[j] = (float4){0.f, 0.f, 0.f, 0.f};
        int i = lo;
        for (; i + 8 <= hi; i += 8) {
            float4 r[8];
            #pragma unroll
            for (int j = 0; j < 8; ++j)
                r[j] = *(const float4*)(bbase + (size_t)sh.p.list[i + j] * cH + col);
            #pragma unroll
            for (int j = 0; j < 8; ++j) {
                a[j].x += r[j].x; a[j].y += r[j].y;
                a[j].z += r[j].z; a[j].w += r[j].w;
            }
        }
        for (; i < hi; ++i) {
            float4 r0 = *(const float4*)(bbase + (size_t)sh.p.list[i] * cH + col);
            a[0].x += r0.x; a[0].y += r0.y; a[0].z += r0.z; a[0].w += r0.w;
        }
        #pragma unroll
        for (int j = 1; j < 8; ++j) {
            a[0].x += a[j].x; a[0].y += a[j].y;
            a[0].z += a[j].z; a[0].w += a[j].w;
        }
        float s0 = a[0].x, s1 = a[0].y, s2 = a[0].z, s3 = a[0].w;
        if (grp) {
            sh.p.ps[grp - 1][t][0] = s0; sh.p.ps[grp - 1][t][1] = s1;
            sh.p.ps[grp - 1][t][2] = s2; sh.p.ps[grp - 1][t][3] = s3;
        }
        __syncthreads();
        if (grp == 0) {
            float inv = 1.0f / (float)c;
            s0 += sh.p.ps[0][t][0] + sh.p.ps[1][t][0] + sh.p.ps[2][t][0];
            s1 += sh.p.ps[0][t][1] + sh.p.ps[1][t][1] + sh.p.ps[2][t][1];
            s2 += sh.p.ps[0][t][2] + sh.p.ps[1][t][2] + sh.p.ps[2][t][2];
            s3 += sh.p.ps[0][t][3] + sh.p.ps[1][t][3] + sh.p.ps[2][t][3];
            __hip_bfloat16* xr = xb + (size_t)bn * cH + col;
            xr[0] = __float2bfloat16(s0 * inv);
            xr[1] = __float2bfloat16(s1 * inv);
            xr[2] = __float2bfloat16(s2 * inv);
            xr[3] = __float2bfloat16(s3 * inv);
        }
    } else {
        // ---------------- wconv: 3 tiles per block ----------------
        int sub = tid >> 8;                         // 0..2
        int t   = tid & 255;
        int bi = (blockIdx.x - cM) * 3 + sub;       // 0..1151 = (12 x 12 x 8)
        int bx = bi % 12, by = (bi / 12) % 12, mat = bi / 144;
        int layer = mat >> 2, which = mat & 3;
        const float* W = (which == 0 ? Wq : which == 1 ? Wk : which == 2 ? Wv : Wo)
                         + (size_t)layer * cH * cH;
        int k0 = by * 64, n0 = bx * 64;
        int r = t >> 2, cb = (t & 3) * 16;
        #pragma unroll
        for (int u = 0; u < 4; ++u) {
            float4 w4 = *(const float4*)(W + (size_t)(k0 + r) * cH + n0 + cb + u * 4);
            sh.T[sub][r][cb + u * 4 + 0] = w4.x; sh.T[sub][r][cb + u * 4 + 1] = w4.y;
            sh.T[sub][r][cb + u * 4 + 2] = w4.z; sh.T[sub][r][cb + u * 4 + 3] = w4.w;
        }
        __syncthreads();
        int nn = t >> 2, kseg = (t & 3) * 16;
        __hip_bfloat16 tmp[16] __attribute__((aligned(16)));
        #pragma unroll
        for (int j = 0; j < 16; ++j)
            tmp[j] = __float2bfloat16(sh.T[sub][kseg + j][nn]);
        __hip_bfloat16* dst = wt + ((size_t)mat * cH + n0 + nn) * cH + k0 + kseg;
        *(bf16x8*)(dst)     = *(const bf16x8*)(tmp);
        *(bf16x8*)(dst + 8) = *(const bf16x8*)(tmp + 8);
    }
}

// ---------------------------------------------------------------------------
// 2a) QKV GEMM, full-machine (R7-verified): 288 blocks x 256 thr.
// ---------------------------------------------------------------------------
__global__ __launch_bounds__(256) void qkv_kernel(
    const __hip_bfloat16* __restrict__ x_bf,
    const __hip_bfloat16* __restrict__ wqkv,
    const float* __restrict__ bq, const float* __restrict__ bk,
    const float* __restrict__ bv,
    __hip_bfloat16* __restrict__ q_bf, __hip_bfloat16* __restrict__ k_bf,
    __hip_bfloat16* __restrict__ v_bf)
{
    int tid = threadIdx.x;
    int lane = tid & 63, wave = tid >> 6;
    int l15 = lane & 15, q4 = lane >> 4;
    int mb = blockIdx.x & 7;
    int nb = blockIdx.x >> 3;
    int mat = nb / 12, hh = nb % 12;

    const __hip_bfloat16* Arow = x_bf
        + (size_t)(mb * 64 + wave * 16 + l15) * cH + q4 * 8;
    const __hip_bfloat16* Brow = wqkv + (size_t)mat * cH * cH
        + (size_t)(hh * 64 + l15) * cH + q4 * 8;

    f32x4 acc[4];
    #pragma unroll
    for (int nt = 0; nt < 4; ++nt) acc[nt] = (f32x4){0.f, 0.f, 0.f, 0.f};

    bf16x8 a, bw[4], an, bn[4];
    a = *(const bf16x8*)(Arow);
    #pragma unroll
    for (int nt = 0; nt < 4; ++nt)
        bw[nt] = *(const bf16x8*)(Brow + (size_t)nt * 16 * cH);
    #pragma unroll 4
    for (int k0 = 0; k0 < cH; k0 += 32) {
        if (k0 + 32 < cH) {
            an = *(const bf16x8*)(Arow + k0 + 32);
            #pragma unroll
            for (int nt = 0; nt < 4; ++nt)
                bn[nt] = *(const bf16x8*)(Brow + (size_t)nt * 16 * cH + k0 + 32);
        }
        #pragma unroll
        for (int nt = 0; nt < 4; ++nt)
            acc[nt] = __builtin_amdgcn_mfma_f32_16x16x32_bf16(a, bw[nt], acc[nt], 0, 0, 0);
        a = an;
        #pragma unroll
        for (int nt = 0; nt < 4; ++nt) bw[nt] = bn[nt];
    }

    const float* bias = mat == 0 ? bq : mat == 1 ? bk : bv;
    __hip_bfloat16* dst = (mat == 0 ? q_bf : mat == 1 ? k_bf : v_bf)
                          + (size_t)(mb * cNH + hh) * 4096;
    float qs = (mat == 0) ? 0.125f : 1.0f;
    #pragma unroll
    for (int nt = 0; nt < 4; ++nt) {
        int col = nt * 16 + l15;
        float bv_ = bias[hh * 64 + col];
        #pragma unroll
        for (int r = 0; r < 4; ++r) {
            int s = wave * 16 + q4 * 4 + r;
            dst[(size_t)s * 64 + col] = __float2bfloat16((acc[nt][r] + bv_) * qs);
        }
    }
}

// ---------------------------------------------------------------------------
// 2b) Attention, all-MFMA (R7-verified, true ~4us): 96 blocks x 256 thr.
// ---------------------------------------------------------------------------
struct Attn2Shared {
    float S[cNS][cNS + 4];
    unsigned short Vt[cDH][cNS + 8];
    unsigned short P[cNS][cNS + 8];
};

__global__ __launch_bounds__(256) void attn2_kernel(
    const __hip_bfloat16* __restrict__ q_bf,
    const __hip_bfloat16* __restrict__ k_bf,
    const __hip_bfloat16* __restrict__ v_bf,
    __hip_bfloat16* __restrict__ ctx_bf)
{
    __shared__ Attn2Shared sh;
    int tid = threadIdx.x;
    int lane = tid & 63, wave = tid >> 6;
    int l15 = lane & 15, q4 = lane >> 4;
    int bh = blockIdx.x, b = bh / cNH, h = bh % cNH;
    const __hip_bfloat16* qp = q_bf + (size_t)bh * 4096;
    const __hip_bfloat16* kp = k_bf + (size_t)bh * 4096;
    const __hip_bfloat16* vp = v_bf + (size_t)bh * 4096;

    // stage V^T into LDS
    #pragma unroll
    for (int i = 0; i < 2; ++i) {
        int idx = tid + i * 256;
        int s = idx >> 3, c0 = (idx & 7) * 8;
        bf16x8 v8 = *(const bf16x8*)(vp + (size_t)s * 64 + c0);
        #pragma unroll
        for (int j = 0; j < 8; ++j)
            sh.Vt[c0 + j][s] = (unsigned short)v8[j];
    }

    // QK^T
    {
        bf16x8 aq0 = *(const bf16x8*)(qp + (size_t)(wave * 16 + l15) * 64 + q4 * 8);
        bf16x8 aq1 = *(const bf16x8*)(qp + (size_t)(wave * 16 + l15) * 64 + 32 + q4 * 8);
        #pragma unroll
        for (int ct = 0; ct < 4; ++ct) {
            bf16x8 bk0 = *(const bf16x8*)(kp + (size_t)(ct * 16 + l15) * 64 + q4 * 8);
            bf16x8 bk1 = *(const bf16x8*)(kp + (size_t)(ct * 16 + l15) * 64 + 32 + q4 * 8);
            f32x4 sc = (f32x4){0.f, 0.f, 0.f, 0.f};
            sc = __builtin_amdgcn_mfma_f32_16x16x32_bf16(aq0, bk0, sc, 0, 0, 0);
            sc = __builtin_amdgcn_mfma_f32_16x16x32_bf16(aq1, bk1, sc, 0, 0, 0);
            #pragma unroll
            for (int r = 0; r < 4; ++r)
                sh.S[wave * 16 + q4 * 4 + r][ct * 16 + l15] = sc[r];
        }
    }
    __syncthreads();

    {   // softmax
        int row = tid >> 2, jq = tid & 3;
        float e[16];
        float m = -1e30f;
        #pragma unroll
        for (int c = 0; c < 16; ++c) { e[c] = sh.S[row][jq * 16 + c]; m = fmaxf(m, e[c]); }
        m = fmaxf(m, __shfl_xor(m, 1));
        m = fmaxf(m, __shfl_xor(m, 2));
        float s = 0.f;
        #pragma unroll
        for (int c = 0; c < 16; ++c) { e[c] = __expf(e[c] - m); s += e[c]; }
        s += __shfl_xor(s, 1);
        s += __shfl_xor(s, 2);
        float inv = 1.0f / s;
        #pragma unroll
        for (int c = 0; c < 16; ++c) sh.P[row][jq * 16 + c] = f2b(e[c] * inv);
    }
    __syncthreads();

    // PV
    {
        bf16x8 ap0 = *(const bf16x8*)&sh.P[wave * 16 + l15][q4 * 8];
        bf16x8 ap1 = *(const bf16x8*)&sh.P[wave * 16 + l15][32 + q4 * 8];
        #pragma unroll
        for (int dt = 0; dt < 4; ++dt) {
            bf16x8 bv0 = *(const bf16x8*)&sh.Vt[dt * 16 + l15][q4 * 8];
            bf16x8 bv1 = *(const bf16x8*)&sh.Vt[dt * 16 + l15][32 + q4 * 8];
            f32x4 o = (f32x4){0.f, 0.f, 0.f, 0.f};
            o = __builtin_amdgcn_mfma_f32_16x16x32_bf16(ap0, bv0, o, 0, 0, 0);
            o = __builtin_amdgcn_mfma_f32_16x16x32_bf16(ap1, bv1, o, 0, 0, 0);
            #pragma unroll
            for (int r = 0; r < 4; ++r) {
                int q = wave * 16 + q4 * 4 + r;
                ctx_bf[(size_t)(b * cNS + q) * cH + h * cDH + dt * 16 + l15] =
                    __float2bfloat16(o[r]);
            }
        }
    }
}

// ---------------------------------------------------------------------------
// 3) O-GEMM + bias + GELU (baseline, true ~5us). Grid (24,8).
// ---------------------------------------------------------------------------
__global__ __launch_bounds__(256) void ogemm_kernel(
    const __hip_bfloat16* __restrict__ A,
    const __hip_bfloat16* __restrict__ Wt,
    const float* __restrict__ bias,
    __hip_bfloat16* __restrict__ C)
{
    int lane = threadIdx.x & 63;
    int wave = threadIdx.x >> 6;
    int l15 = lane & 15, q4 = lane >> 4;
    int m0 = blockIdx.y * 64 + wave * 16;
    int n0 = blockIdx.x * 32;

    const __hip_bfloat16* Arow = A  + (size_t)(m0 + l15) * cH + q4 * 8;
    const __hip_bfloat16* Wr0  = Wt + (size_t)(n0 + l15) * cH + q4 * 8;
    const __hip_bfloat16* Wr1  = Wr0 + (size_t)16 * cH;

    f32x4 acc0 = {0.f, 0.f, 0.f, 0.f};
    f32x4 acc1 = {0.f, 0.f, 0.f, 0.f};
    #pragma unroll 8
    for (int k0 = 0; k0 < cH; k0 += 32) {
        bf16x8 a  = *(const bf16x8*)(Arow + k0);
        bf16x8 b0 = *(const bf16x8*)(Wr0 + k0);
        bf16x8 b1 = *(const bf16x8*)(Wr1 + k0);
        acc0 = __builtin_amdgcn_mfma_f32_16x16x32_bf16(a, b0, acc0, 0, 0, 0);
        acc1 = __builtin_amdgcn_mfma_f32_16x16x32_bf16(a, b1, acc1, 0, 0, 0);
    }
    #pragma unroll
    for (int nt = 0; nt < 2; ++nt) {
        const f32x4 acc = nt == 0 ? acc0 : acc1;
        int col = n0 + nt * 16 + l15;
        float bv = bias[col];
        #pragma unroll
        for (int r = 0; r < 4; ++r) {
            float v = acc[r] + bv;
            v = 0.5f * v * (1.0f + erff(v * 0.70710678118654752f));
            C[(size_t)(m0 + q4 * 4 + r) * cH + col] = __float2bfloat16(v);
        }
    }
}

// ---------------------------------------------------------------------------
// 4) LayerNorm (baseline, true ~3us). 512 blocks.
// ---------------------------------------------------------------------------
__global__ __launch_bounds__(256) void ln_kernel(
    const __hip_bfloat16* __restrict__ h, const float* __restrict__ g,
    const float* __restrict__ bb, __hip_bfloat16* __restrict__ xb,
    float* __restrict__ outf)
{
    int row = blockIdx.x;
    const __hip_bfloat16* r = h + (size_t)row * cH;
    int tid = threadIdx.x;
    float v0 = __bfloat162float(r[tid]);
    float v1 = __bfloat162float(r[tid + 256]);
    float v2 = __bfloat162float(r[tid + 512]);
    float s = v0 + v1 + v2;
    __shared__ float red[4];
    #pragma unroll
    for (int o = 32; o; o >>= 1) s += __shfl_xor(s, o);
    if ((tid & 63) == 0) red[tid >> 6] = s;
    __syncthreads();
    float mu = (red[0] + red[1] + red[2] + red[3]) * (1.0f / 768.0f);
    float d0 = v0 - mu, d1 = v1 - mu, d2 = v2 - mu;
    float ss = d0 * d0 + d1 * d1 + d2 * d2;
    __syncthreads();
    #pragma unroll
    for (int o = 32; o; o >>= 1) ss += __shfl_xor(ss, o);
    if ((tid & 63) == 0) red[tid >> 6] = ss;
    __syncthreads();
    float var = (red[0] + red[1] + red[2] + red[3]) * (1.0f / 768.0f);
    float inv = rsqrtf(var + 1e-12f);
    float o0 = d0 * inv * g[tid]       + bb[tid];
    float o1 = d1 * inv * g[tid + 256] + bb[tid + 256];
    float o2 = d2 * inv * g[tid + 512] + bb[tid + 512];
    __hip_bfloat16* xr = xb + (size_t)row * cH;
    xr[tid]       = __float2bfloat16(o0);
    xr[tid + 256] = __float2bfloat16(o1);
    xr[tid + 512] = __float2bfloat16(o2);
    if (outf) {
        float* orow = outf + (size_t)row * cH;
        orow[tid] = o0; orow[tid + 256] = o1; orow[tid + 512] = o2;
    }
}

// ---------------------------------------------------------------------------
extern "C" void kernel_launch(void* const* d_in, const int* in_sizes, int n_in,
                              void* d_out, int out_size, void* d_ws, size_t ws_size,
                              hipStream_t stream) {
    const int*   sent_ind = (const int*)d_in[0];
    const float* start    = (const float*)d_in[1];
    const float* Wq = (const float*)d_in[2];
    const float* bq = (const float*)d_in[3];
    const float* Wk = (const float*)d_in[4];
    const float* bk = (const float*)d_in[5];
    const float* Wv = (const float*)d_in[6];
    const float* bv = (const float*)d_in[7];
    const float* Wo = (const float*)d_in[8];
    const float* bo = (const float*)d_in[9];
    const float* ln_g = (const float*)d_in[10];
    const float* ln_b = (const float*)d_in[11];
    float* out = (float*)d_out;

    char* w = (char*)d_ws;
    const size_t MH = 786432;  // M*H bf16 bytes
    __hip_bfloat16* wt     = (__hip_bfloat16*)w;
    __hip_bfloat16* x_bf   = (__hip_bfloat16*)(w + 9437184);
    __hip_bfloat16* ctx_bf = (__hip_bfloat16*)(w + 9437184 + MH);
    __hip_bfloat16* hb     = (__hip_bfloat16*)(w + 9437184 + 2 * MH);
    __hip_bfloat16* q_bf   = (__hip_bfloat16*)(w + 9437184 + 3 * MH);
    __hip_bfloat16* k_bf   = (__hip_bfloat16*)(w + 9437184 + 4 * MH);
    __hip_bfloat16* v_bf   = (__hip_bfloat16*)(w + 9437184 + 5 * MH);

    prep_kernel<<<cM + 384, 768, 0, stream>>>(sent_ind, start, x_bf,
                                              Wq, Wk, Wv, Wo, wt);

    for (int i = 0; i < cL; ++i) {
        const __hip_bfloat16* wqkv = wt + (size_t)(i * 4) * cH * cH;
        const __hip_bfloat16* wto  = wt + (size_t)(i * 4 + 3) * cH * cH;
        qkv_kernel<<<288, 256, 0, stream>>>(
            x_bf, wqkv, bq + (size_t)i * cH, bk + (size_t)i * cH, bv + (size_t)i * cH,
            q_bf, k_bf, v_bf);
        attn2_kernel<<<cB * cNH, 256, 0, stream>>>(q_bf, k_bf, v_bf, ctx_bf);
        ogemm_kernel<<<dim3(24, 8), 256, 0, stream>>>(
            ctx_bf, wto, bo + (size_t)i * cH, hb);
        ln_kernel<<<cM, 256, 0, stream>>>(
            hb, ln_g + (size_t)i * cH, ln_b + (size_t)i * cH,
            x_bf, (i == cL - 1) ? out : nullptr);
    }
}